// Round 4
// baseline (411.863 us; speedup 1.0000x reference)
//
#include <hip/hip_runtime.h>

// Problem: x [B=256,1,512,512] f32; weights [512,4,1]; biases [512,1].
// out[b,i] = relu( dot(ring_means(b,i,0..3), weights[i,:,0]) + biases[i] )
// ring per corner at (r,c): tl max(r,c), tr max(r,511-c), bl max(511-r,c),
// br max(511-r,511-c).
//
// R1/R3 lesson: in-loop __shfl_down reductions (384 ds_bpermute/wave,
// serialized ~120cyc latency) dominated (~46K cyc/wave, all pipes idle).
// v5: per-lane REGISTER row-bins (static 16-row unroll) + ONE LDS-transpose
// reduction per wave at the end (8 shuffles/wave total). Col bins unchanged.
// Partials to global (plain stores), kernel 2 folds + linear + relu.

#define HH 512
#define WW 512
#define NRING 512
#define NB (4 * NRING)   // bins per image: [corner][ring]

// grid: B*8 blocks of 256 threads (4 waves). Block = (image b, 64-row chunk).
// Wave w owns rows rbase = chunk*64 + w*16 .. +15.
template<bool PARTIALS>
__global__ __launch_bounds__(256)
void ring_sum_kernel(const float* __restrict__ x, float* __restrict__ ws) {
    __shared__ float bins[NB];           // [corner][ring], 8 KiB
    __shared__ float sc[4][64][17];      // per-wave transpose scratch, 17 KiB
    const int tid  = threadIdx.x;
    const int lane = tid & 63;
    const int wave = tid >> 6;
    const int b     = blockIdx.x >> 3;
    const int chunk = blockIdx.x & 7;

    for (int t = tid; t < NB; t += 256) bins[t] = 0.f;
    __syncthreads();

    // col bins: ring = c (TL,BL) or 511-c (TR,BR); lane owns cols cA..cA+3, cB..cB+3
    float vTL[8] = {0,0,0,0,0,0,0,0};
    float vTR[8] = {0,0,0,0,0,0,0,0};
    float vBL[8] = {0,0,0,0,0,0,0,0};
    float vBR[8] = {0,0,0,0,0,0,0,0};
    // row bins: per-lane partial of row-determined sums, k = r - rbase
    float rTL[16], rTR[16], rBL[16], rBR[16];
    #pragma unroll
    for (int k = 0; k < 16; ++k) { rTL[k]=0.f; rTR[k]=0.f; rBL[k]=0.f; rBR[k]=0.f; }

    const float4* img = (const float4*)x + (size_t)b * (HH * WW / 4);
    const int cA = 4 * lane;        // columns cA..cA+3
    const int cB = 256 + 4 * lane;  // columns cB..cB+3
    const int rbase = chunk * 64 + wave * 16;
    const bool top = (rbase < 256); // wave-uniform; 16-row span never straddles

    // 2-row-ahead software pipeline (24 data VGPRs)
    float4 bufA[3], bufB[3];
    {
        const float4* rp0 = img + (size_t)rbase * (WW / 4);
        bufA[0] = rp0[lane];  bufB[0] = rp0[64 + lane];
        const float4* rp1 = img + (size_t)(rbase + 1) * (WW / 4);
        bufA[1] = rp1[lane];  bufB[1] = rp1[64 + lane];
    }

    #pragma unroll
    for (int k = 0; k < 16; ++k) {
        const int cur = k % 3, nx = (k + 2) % 3;
        if (k < 14) {
            const float4* rp = img + (size_t)(rbase + k + 2) * (WW / 4);
            bufA[nx] = rp[lane];  bufB[nx] = rp[64 + lane];
        }
        const int r = rbase + k;
        const int s = 511 - r;
        const float4 a  = bufA[cur];
        const float4 bb = bufB[cur];

        if (top) {
            #pragma unroll
            for (int e = 0; e < 4; ++e) {       // group A: c < 256
                float v = (&a.x)[e]; int c = cA + e;
                rBL[k] += v;                     // bl uniform (ring 511-r)
                vTR[e] += v;                     // tr col bin (ring 511-c)
                float sel  = (c <= r) ? v : 0.f; rTL[k] += sel;  vTL[e] += v - sel;
                float sel2 = (c >= r) ? v : 0.f; rBR[k] += sel2; vBR[e] += v - sel2;
            }
            #pragma unroll
            for (int e = 0; e < 4; ++e) {       // group B: c >= 256
                float v = (&bb.x)[e]; int c = cB + e;
                rBR[k] += v;                     // br uniform (ring 511-r)
                vTL[4 + e] += v;                 // tl col bin (ring c)
                float sel  = (c >= s) ? v : 0.f; rTR[k] += sel;  vTR[4 + e] += v - sel;
                float sel2 = (c <= s) ? v : 0.f; rBL[k] += sel2; vBL[4 + e] += v - sel2;
            }
        } else {
            #pragma unroll
            for (int e = 0; e < 4; ++e) {       // group A
                float v = (&a.x)[e]; int c = cA + e;
                rTL[k] += v;                     // tl uniform (ring r)
                vBR[e] += v;                     // br col bin (ring 511-c)
                float sel  = (c >= s) ? v : 0.f; rTR[k] += sel;  vTR[e] += v - sel;
                float sel2 = (c <= s) ? v : 0.f; rBL[k] += sel2; vBL[e] += v - sel2;
            }
            #pragma unroll
            for (int e = 0; e < 4; ++e) {       // group B
                float v = (&bb.x)[e]; int c = cB + e;
                rTR[k] += v;                     // tr uniform (ring r)
                vBL[4 + e] += v;                 // bl col bin (ring c)
                float sel  = (c <= r) ? v : 0.f; rTL[k] += sel;  vTL[4 + e] += v - sel;
                float sel2 = (c >= r) ? v : 0.f; rBR[k] += sel2; vBR[4 + e] += v - sel2;
            }
        }
    }

    // ---- epilogue: reduce each row-bin array across the wave's 64 lanes ----
    // LDS transpose: lane writes its 16 partials; lane (q,kk)=(lane>>4,lane&15)
    // sums quarter q of row-index kk; 2 shfl_downs combine quarters.
    const int q  = lane >> 4;
    const int kk = lane & 15;
#define REDUCE_CORNER(ARR, CIDX, RING_OF_KK)                                   \
    {                                                                          \
        _Pragma("unroll")                                                      \
        for (int j = 0; j < 16; ++j) sc[wave][lane][j] = ARR[j];               \
        __syncthreads();                                                       \
        float acc = 0.f;                                                       \
        _Pragma("unroll")                                                      \
        for (int l = 0; l < 16; ++l) acc += sc[wave][q * 16 + l][kk];          \
        acc += __shfl_down(acc, 32);                                           \
        acc += __shfl_down(acc, 16);                                           \
        if (lane < 16) atomicAdd(&bins[(CIDX) * NRING + (RING_OF_KK)], acc);   \
        __syncthreads();                                                       \
    }
    REDUCE_CORNER(rTL, 0, rbase + kk)
    REDUCE_CORNER(rTR, 1, rbase + kk)
    REDUCE_CORNER(rBL, 2, 511 - (rbase + kk))
    REDUCE_CORNER(rBR, 3, 511 - (rbase + kk))
#undef REDUCE_CORNER

    // ---- flush per-lane col bins (ring depends only on owned column c) ----
    #pragma unroll
    for (int e = 0; e < 8; ++e) {
        int c = (e < 4) ? (cA + e) : (cB + e - 4);
        atomicAdd(&bins[0 * NRING + c],         vTL[e]);
        atomicAdd(&bins[1 * NRING + (511 - c)], vTR[e]);
        atomicAdd(&bins[2 * NRING + c],         vBL[e]);
        atomicAdd(&bins[3 * NRING + (511 - c)], vBR[e]);
    }
    __syncthreads();

    if (PARTIALS) {
        float* outp = ws + ((size_t)b * 8 + chunk) * NB;
        for (int t = tid; t < NB; t += 256) outp[t] = bins[t];
    } else {
        float* outp = ws + (size_t)b * NB;
        for (int t = tid; t < NB; t += 256) atomicAdd(&outp[t], bins[t]);
    }
}

// ------------- Kernel 2: fold partials + mean + linear + bias + relu -------
__global__ __launch_bounds__(512)
void linear_kernel(const float* __restrict__ ws, const float* __restrict__ wts,
                   const float* __restrict__ bias, float* __restrict__ out,
                   int nparts) {
    const int b = blockIdx.x;
    const int i = threadIdx.x;   // ring index
    const float* base = ws + (size_t)b * nparts * NB;
    float s0 = 0.f, s1 = 0.f, s2 = 0.f, s3 = 0.f;
    for (int p = 0; p < nparts; ++p) {
        const float* pb = base + (size_t)p * NB;
        s0 += pb[0 * NRING + i];
        s1 += pb[1 * NRING + i];
        s2 += pb[2 * NRING + i];
        s3 += pb[3 * NRING + i];
    }
    float4 w  = ((const float4*)wts)[i];          // weights[i][0..3][0]
    float inv = 1.0f / (float)(2 * i + 1);
    float val = (s0 * w.x + s1 * w.y + s2 * w.z + s3 * w.w) * inv + bias[i];
    out[b * NRING + i] = fmaxf(val, 0.0f);
}

extern "C" void kernel_launch(void* const* d_in, const int* in_sizes, int n_in,
                              void* d_out, int out_size, void* d_ws, size_t ws_size,
                              hipStream_t stream) {
    const float* x    = (const float*)d_in[0];
    const float* wts  = (const float*)d_in[1];
    const float* bias = (const float*)d_in[2];
    float* out = (float*)d_out;

    const int B = in_sizes[0] / (HH * WW);   // 256
    float* ws = (float*)d_ws;

    const size_t need = (size_t)B * 8 * NB * sizeof(float);   // 16 MiB
    if (ws_size >= need) {
        ring_sum_kernel<true><<<dim3(B * 8), dim3(256), 0, stream>>>(x, ws);
        linear_kernel<<<dim3(B), dim3(512), 0, stream>>>(ws, wts, bias, out, 8);
    } else {
        hipMemsetAsync(ws, 0, (size_t)B * NB * sizeof(float), stream);
        ring_sum_kernel<false><<<dim3(B * 8), dim3(256), 0, stream>>>(x, ws);
        linear_kernel<<<dim3(B), dim3(512), 0, stream>>>(ws, wts, bias, out, 1);
    }
}